// Round 4
// baseline (639.291 us; speedup 1.0000x reference)
//
#include <hip/hip_runtime.h>
#include <stdint.h>

// ---------------------------------------------------------------------------
// QuantQwenAttentionV2 fused pipeline, MI355X (gfx950)
//
//  k_zero       : zero amax scalars in ws
//  k_absmax     : per-tensor absmax of hidden (atomicMax on float bits)
//  k_quant_w    : per-row 4-bit weight fake-quant -> int8 [-8,7] + scale
//  k_quant_act  : per-tensor 8-bit activation fake-quant -> int8 [-128,127]
//  k_gemm       : int8 MFMA GEMM (exact integer path), fused epilogues:
//                   epi0: Q  = rope(y)*2^12/sqrt(d) -> f16 hi/lo [h][s][d]
//                   epi1: K  = rope(y)*2^12         -> f16 hi/lo [g][s][d]
//                   epi2: V  = y*2^6                -> f16 hi/lo transposed [g][d][s]
//                   epi3: O-proj -> fp32 d_out
//                 1-D grid, XCD-chunked bijective swizzle (T1/m204).
//  k_attn       : flash attention, 3-term hi/lo **f16** MFMA (pre-scaled by
//                 powers of 2 so residuals stay normal; S unscaled by 2^-24,
//                 O by 2^-20; ~2^-22 relative accuracy ~ fp32), fp32 online
//                 softmax (T13 defer-rescale), fused absmax. P scratch aliases
//                 the K LDS tile (per-wave quarters) -> 64KB LDS, 2 blocks/CU.
// ---------------------------------------------------------------------------

#define S_LEN 2048
#define HID   3584
#define NH    28
#define NKV   4
#define HD    128
#define GQA   7      // NH / NKV
#define KD    3584   // inner dim of projections

typedef signed char i8;
typedef unsigned short u16;
typedef __attribute__((ext_vector_type(4))) int      v4i;
typedef __attribute__((ext_vector_type(4))) float    v4f;
typedef __attribute__((ext_vector_type(8))) _Float16 f16x8;  // 8 f16 (4 VGPRs)
typedef __attribute__((ext_vector_type(4))) float    f32x4;

// scales (powers of 2, folded into existing multiplies; keep f16 residuals normal)
#define QK_SCALE   4096.0f                    // 2^12 on Q and on K
#define S_UNSCALE  5.9604644775390625e-8f     // 2^-24
#define V_SCALE    64.0f                      // 2^6
#define P_SCALE    16384.0f                   // 2^14
#define O_UNSCALE  9.5367431640625e-7f        // 2^-20

#define GLOAD_LDS(g, l) __builtin_amdgcn_global_load_lds( \
    (__attribute__((address_space(1))) void*)(g),          \
    (__attribute__((address_space(3))) void*)(l), 16, 0, 0)

static __device__ __forceinline__ u16 f16bits(_Float16 h) {
  u16 u; __builtin_memcpy(&u, &h, 2); return u;
}
// split x into f16 hi + f16 lo (hi = RNE(x), lo = RNE(x - hi)); ~22-bit total
static __device__ __forceinline__ void splitf16(float x, u16& hb, u16& lb) {
  _Float16 h = (_Float16)x;
  float r = x - (float)h;          // exact (Sterbenz)
  _Float16 l = (_Float16)r;
  hb = f16bits(h); lb = f16bits(l);
}

// ---------------------------------------------------------------------------
__global__ void k_zero(float* p) {
  if (threadIdx.x < 8) p[threadIdx.x] = 0.0f;
}

// grid-stride absmax over n floats (n % 4 == 0), atomicMax on positive float bits
__global__ void k_absmax(const float* __restrict__ x, long long n, unsigned* __restrict__ out) {
  long long i0 = ((long long)blockIdx.x * blockDim.x + threadIdx.x) * 4;
  long long stride = (long long)gridDim.x * blockDim.x * 4;
  float m = 0.0f;
  for (long long i = i0; i < n; i += stride) {
    f32x4 v = *(const f32x4*)(x + i);
    m = fmaxf(m, fmaxf(fmaxf(fabsf(v.x), fabsf(v.y)), fmaxf(fabsf(v.z), fabsf(v.w))));
  }
  #pragma unroll
  for (int o = 32; o > 0; o >>= 1) m = fmaxf(m, __shfl_xor(m, o, 64));
  __shared__ float sm[4];
  if ((threadIdx.x & 63) == 0) sm[threadIdx.x >> 6] = m;
  __syncthreads();
  if (threadIdx.x == 0) {
    m = fmaxf(fmaxf(sm[0], sm[1]), fmaxf(sm[2], sm[3]));
    atomicMax(out, __float_as_uint(m));
  }
}

// per-tensor 8-bit symmetric fake-quant -> int8
__global__ void k_quant_act(const float* __restrict__ x, i8* __restrict__ q,
                            const unsigned* __restrict__ amax, long long n) {
  float s = fmaxf(__uint_as_float(*amax) / 127.0f, 1e-8f);
  long long i = ((long long)blockIdx.x * blockDim.x + threadIdx.x) * 4;
  if (i >= n) return;
  f32x4 v = *(const f32x4*)(x + i);
  char4 c;
  c.x = (char)fminf(fmaxf(rintf(v.x / s), -128.0f), 127.0f);
  c.y = (char)fminf(fmaxf(rintf(v.y / s), -128.0f), 127.0f);
  c.z = (char)fminf(fmaxf(rintf(v.z / s), -128.0f), 127.0f);
  c.w = (char)fminf(fmaxf(rintf(v.w / s), -128.0f), 127.0f);
  *(char4*)(q + i) = c;
}

// per-row 4-bit symmetric weight fake-quant -> int8 in [-8,7]; one block per row
__global__ void k_quant_w(const float* __restrict__ w, i8* __restrict__ wq,
                          float* __restrict__ sw) {
  const int row = blockIdx.x;
  const float2* wr = (const float2*)(w + (long long)row * KD);
  float2 v[7];
  float m = 0.0f;
  #pragma unroll
  for (int j = 0; j < 7; j++) {            // 1792 float2 = 3584 floats
    v[j] = wr[threadIdx.x + 256 * j];
    m = fmaxf(m, fmaxf(fabsf(v[j].x), fabsf(v[j].y)));
  }
  #pragma unroll
  for (int o = 32; o > 0; o >>= 1) m = fmaxf(m, __shfl_xor(m, o, 64));
  __shared__ float sm[4];
  if ((threadIdx.x & 63) == 0) sm[threadIdx.x >> 6] = m;
  __syncthreads();
  const float mm = fmaxf(fmaxf(sm[0], sm[1]), fmaxf(sm[2], sm[3]));
  const float s = fmaxf(mm / 7.0f, 1e-8f);
  if (threadIdx.x == 0) sw[row] = s;
  u16* o = (u16*)(wq + (long long)row * KD);
  #pragma unroll
  for (int j = 0; j < 7; j++) {
    const int c0 = (int)fminf(fmaxf(rintf(v[j].x / s), -8.0f), 7.0f);
    const int c1 = (int)fminf(fmaxf(rintf(v[j].y / s), -8.0f), 7.0f);
    o[threadIdx.x + 256 * j] = (u16)((c0 & 0xff) | ((c1 & 0xff) << 8));
  }
}

// ---------------------------------------------------------------------------
// int8 GEMM: C[m][n] = s_a*sw[n]*sum_k A[m,k]*W[n,k] (+bias), fused epilogues.
// Block: 256 thr (4 waves, wave tile 32x128). BM=BN=128, BK=64.
// LDS tiles [128][64] i8; 16B chunks XOR-swizzled with ((row>>1)&3) so the
// mfma ds_read_b128 fragment reads are 2-way (free) instead of 8-way.
// 1-D grid, nwg%8==0. XCD-chunked bijective swizzle: xcd = orig%8 owns a
// contiguous chunk of (ct,mb) work -> each XCD's L2 holds ~4 B-panels (~2MB)
// instead of all 36 (~16MB).
// kind==0: QKV fused over 36 col-tiles (28 Q heads, 4 K kv-heads, 4 V kv-heads)
// kind==1: O-projection (W0=wo8, sw0=swo, no bias), writes fp32 out.
__global__ __launch_bounds__(256, 3) void k_gemm(
    const i8* __restrict__ Aq,
    const i8* __restrict__ W0, const i8* __restrict__ W1, const i8* __restrict__ W2,
    const float* __restrict__ sw0, const float* __restrict__ sw1, const float* __restrict__ sw2,
    const float* __restrict__ b0, const float* __restrict__ b1, const float* __restrict__ b2,
    const float* __restrict__ cosb, const float* __restrict__ sinb,
    const unsigned* __restrict__ amax_slot,
    u16* __restrict__ qhi, u16* __restrict__ qlo,
    u16* __restrict__ khi, u16* __restrict__ klo,
    u16* __restrict__ vthi, u16* __restrict__ vtlo,
    float* __restrict__ outO, int kind) {
  __shared__ i8 As[128 * 64];
  __shared__ i8 Bs[128 * 64];
  const int tid = threadIdx.x, wid = tid >> 6, lane = tid & 63;

  // bijective XCD chunking (m204): orig%8 = XCD, chunk of nwg/8 work items
  const int q8 = (int)gridDim.x >> 3;
  const int orig = blockIdx.x;
  const int wgid = (orig & 7) * q8 + (orig >> 3);
  const int ct = wgid >> 4;     // 16 mb-tiles per ct
  const int mb = wgid & 15;

  const i8* Bw; const float* sw; const float* bias; int epi; int nbase;
  if (kind == 1)      { Bw = W0; sw = sw0; bias = nullptr; epi = 3; nbase = ct * 128; }
  else if (ct < 28)   { Bw = W0; sw = sw0; bias = b0;      epi = 0; nbase = ct * 128; }
  else if (ct < 32)   { Bw = W1; sw = sw1; bias = b1;      epi = 1; nbase = (ct - 28) * 128; }
  else                { Bw = W2; sw = sw2; bias = b2;      epi = 2; nbase = (ct - 32) * 128; }

  const float s_a = fmaxf(__uint_as_float(*amax_slot) / 127.0f, 1e-8f);

  v4i acc[2][8];
  #pragma unroll
  for (int a = 0; a < 2; a++)
    #pragma unroll
    for (int b = 0; b < 8; b++) acc[a][b] = (v4i)(0);

  const long long arow0 = (long long)mb * 128 * KD;
  const long long brow0 = (long long)nbase * KD;

  for (int kt = 0; kt < KD / 64; ++kt) {
    const int k0 = kt * 64;
    #pragma unroll
    for (int j = 0; j < 2; j++) {
      const int c = tid + 256 * j;
      const int r = c >> 2, seg = c & 3;
      const int so = (seg ^ ((r >> 1) & 3)) << 4;  // pre-swizzled global source
      GLOAD_LDS(Aq + arow0 + (long long)r * KD + k0 + so, As + c * 16);
      GLOAD_LDS(Bw + brow0 + (long long)r * KD + k0 + so, Bs + c * 16);
    }
    __syncthreads();
    v4i af[2];
    #pragma unroll
    for (int mt = 0; mt < 2; mt++) {
      const int rl = wid * 32 + mt * 16 + (lane & 15);
      af[mt] = *(const v4i*)(As + rl * 64 + ((((lane >> 4)) ^ ((rl >> 1) & 3)) << 4));
    }
    #pragma unroll
    for (int nt = 0; nt < 8; nt++) {
      const int rb = nt * 16 + (lane & 15);
      const v4i bfr = *(const v4i*)(Bs + rb * 64 + ((((lane >> 4)) ^ ((rb >> 1) & 3)) << 4));
      acc[0][nt] = __builtin_amdgcn_mfma_i32_16x16x64_i8(af[0], bfr, acc[0][nt], 0, 0, 0);
      acc[1][nt] = __builtin_amdgcn_mfma_i32_16x16x64_i8(af[1], bfr, acc[1][nt], 0, 0, 0);
    }
    __syncthreads();
  }

  // ---- epilogue (C layout: col n = lane&15 + 16*nt, row m = (lane>>4)*4 + r) --
  float y[2][8][4];
  #pragma unroll
  for (int mt = 0; mt < 2; mt++)
    #pragma unroll
    for (int nt = 0; nt < 8; nt++) {
      const int n = nbase + nt * 16 + (lane & 15);
      const float sc = s_a * sw[n];
      const float bb = bias ? bias[n] : 0.0f;
      #pragma unroll
      for (int r = 0; r < 4; r++) y[mt][nt][r] = sc * (float)acc[mt][nt][r] + bb;
    }

  if (epi == 3) {  // O-projection: plain fp32 store
    #pragma unroll
    for (int mt = 0; mt < 2; mt++)
      #pragma unroll
      for (int r = 0; r < 4; r++) {
        const int m_ = mb * 128 + wid * 32 + mt * 16 + ((lane >> 4) << 2) + r;
        #pragma unroll
        for (int nt = 0; nt < 8; nt++)
          outO[(long long)m_ * HID + ct * 128 + nt * 16 + (lane & 15)] = y[mt][nt][r];
      }
  } else if (epi == 2) {  // V: f16 hi/lo split of V*2^6, stored transposed [g][d][s]
    const int gkv = ct - 32;
    #pragma unroll
    for (int mt = 0; mt < 2; mt++)
      #pragma unroll
      for (int nt = 0; nt < 8; nt++) {
        const int d = nt * 16 + (lane & 15);
        const int mbase = mb * 128 + wid * 32 + mt * 16 + ((lane >> 4) << 2);
        ushort4 hv, lv;
        #pragma unroll
        for (int r = 0; r < 4; r++)
          splitf16(y[mt][nt][r] * V_SCALE, ((u16*)&hv)[r], ((u16*)&lv)[r]);
        const long long o = ((long long)(gkv * HD + d)) * S_LEN + mbase;
        *(ushort4*)(vthi + o) = hv;
        *(ushort4*)(vtlo + o) = lv;
      }
  } else {  // Q (epi 0) / K (epi 1): multimodal RoPE, f16 hi/lo of (rope)*scale
    const int head = (epi == 0) ? ct : (ct - 28);
    u16* oh = (epi == 0) ? qhi : khi;
    u16* ol = (epi == 0) ? qlo : klo;
    // Q: 1/sqrt(128) * 2^12 ; K: 2^12
    const float qs = (epi == 0) ? 0.08838834764831845f * QK_SCALE : QK_SCALE;
    #pragma unroll
    for (int mt = 0; mt < 2; mt++)
      #pragma unroll
      for (int r = 0; r < 4; r++) {
        const int m_ = mb * 128 + wid * 32 + mt * 16 + ((lane >> 4) << 2) + r;
        #pragma unroll
        for (int nt = 0; nt < 8; nt++) {
          const int d = nt * 16 + (lane & 15);
          const int sec = (d < 32) ? 0 : ((d < 80) ? 1 : 2);  // mrope [16,24,24]*2
          const long long ci = ((long long)sec * S_LEN + m_) * HD + d;
          const float c = cosb[ci], s = sinb[ci];
          const float part = (nt < 4) ? -y[mt][nt + 4][r] : y[mt][nt - 4][r];
          const float e = (y[mt][nt][r] * c + part * s) * qs;
          const long long o = ((long long)head * S_LEN + m_) * HD + d;
          splitf16(e, oh[o], ol[o]);
        }
      }
  }
}

// ---------------------------------------------------------------------------
// Flash attention. Block = (head, q-tile of 128 rows), 4 waves x 32 q-rows.
// K-tiles of 64 positions staged hi/lo in LDS (XOR-swizzled); V staged from the
// pre-transposed [g][d][s] buffers. S = Q.K^T via 3-term hi/lo f16 MFMA
// (pre-scaled; S*2^-24 at mask), fp32 online softmax (T13 defer-rescale),
// P*2^14 -> per-wave quarter of the dead K tile, O += P.V (3-term), O*2^-20
// at normalize. LDS = 64KB -> 2 blocks/CU (8 waves/CU).
__global__ __launch_bounds__(256, 2) void k_attn(
    const u16* __restrict__ qhi, const u16* __restrict__ qlo,
    const u16* __restrict__ khi, const u16* __restrict__ klo,
    const u16* __restrict__ vthi, const u16* __restrict__ vtlo,
    float* __restrict__ attn, unsigned* __restrict__ amax) {
  const int h = blockIdx.x;
  const int qt = (int)gridDim.y - 1 - (int)blockIdx.y;  // heavy tiles first
  const int g = h / GQA;
  const int tid = threadIdx.x, wid = tid >> 6, lane = tid & 63;

  __shared__ u16 KH[64 * 128], KL[64 * 128];   // [kpos][d], swizzled; P aliases
  __shared__ u16 VH[128 * 64], VL[128 * 64];   // [d][kpos], swizzled
  u16* PH = KH + wid * (32 * 64);              // per-wave P [q 32][kpos 64]
  u16* PL = KL + wid * (32 * 64);

  // Q fragments in registers (A-operand layout: row = lane&15, k chunk = lane>>4)
  f16x8 qh[2][4], ql[2][4];
  #pragma unroll
  for (int mt = 0; mt < 2; mt++) {
    const int row = qt * 128 + wid * 32 + mt * 16 + (lane & 15);
    const long long base = ((long long)h * S_LEN + row) * HD + ((lane >> 4) << 3);
    #pragma unroll
    for (int kc = 0; kc < 4; kc++) {
      qh[mt][kc] = *(const f16x8*)(qhi + base + kc * 32);
      ql[mt][kc] = *(const f16x8*)(qlo + base + kc * 32);
    }
  }

  v4f O[2][8];
  #pragma unroll
  for (int a = 0; a < 2; a++)
    #pragma unroll
    for (int b = 0; b < 8; b++) O[a][b] = (v4f)(0.0f);
  float mrun[2][4], lsum[2][4];
  #pragma unroll
  for (int a = 0; a < 2; a++)
    #pragma unroll
    for (int r = 0; r < 4; r++) { mrun[a][r] = -1e30f; lsum[a][r] = 0.0f; }

  const int qmaxw = qt * 128 + wid * 32 + 31;
  const int ktiles = 2 * qt + 2;
  for (int kt = 0; kt < ktiles; ++kt) {
    const int s0 = kt * 64;
    // stage K hi/lo: 1024 16B-chunks each; rows 256B = 16 chunks, XOR (r&7)
    #pragma unroll
    for (int j = 0; j < 4; j++) {
      const int c = tid + 256 * j;
      const int r = c >> 4, seg = c & 15;
      const long long gb = ((long long)g * S_LEN + s0 + r) * HD + ((seg ^ (r & 7)) << 3);
      GLOAD_LDS(khi + gb, (i8*)KH + c * 16);
      GLOAD_LDS(klo + gb, (i8*)KL + c * 16);
    }
    // stage V^T hi/lo: 1024 chunks each; rows 128B = 8 chunks, XOR (d&7)
    #pragma unroll
    for (int j = 0; j < 4; j++) {
      const int c = tid + 256 * j;
      const int d = c >> 3, seg = c & 7;
      const long long gb = ((long long)(g * HD + d)) * S_LEN + s0 + ((seg ^ (d & 7)) << 3);
      GLOAD_LDS(vthi + gb, (i8*)VH + c * 16);
      GLOAD_LDS(vtlo + gb, (i8*)VL + c * 16);
    }
    __syncthreads();

    const bool active = (s0 <= qmaxw);  // wave-uniform causal skip
    v4f S[2][4];
    if (active) {
      // S = Q.K^T  (C tile: col = kpos = lane&15, row = q = 4*(lane>>4)+reg)
      #pragma unroll
      for (int a = 0; a < 2; a++)
        #pragma unroll
        for (int b = 0; b < 4; b++) S[a][b] = (v4f)(0.0f);
      __builtin_amdgcn_s_setprio(1);
      #pragma unroll
      for (int kc = 0; kc < 4; kc++) {
        #pragma unroll
        for (int nt = 0; nt < 4; nt++) {
          const int rk = nt * 16 + (lane & 15);
          const int ch = kc * 4 + (lane >> 4);
          const int idx = rk * 128 + ((ch ^ (rk & 7)) << 3);
          const f16x8 kh = *(const f16x8*)(KH + idx);
          const f16x8 kl = *(const f16x8*)(KL + idx);
          #pragma unroll
          for (int mt = 0; mt < 2; mt++) {
            S[mt][nt] = __builtin_amdgcn_mfma_f32_16x16x32_f16(qh[mt][kc], kh, S[mt][nt], 0, 0, 0);
            S[mt][nt] = __builtin_amdgcn_mfma_f32_16x16x32_f16(qh[mt][kc], kl, S[mt][nt], 0, 0, 0);
            S[mt][nt] = __builtin_amdgcn_mfma_f32_16x16x32_f16(ql[mt][kc], kh, S[mt][nt], 0, 0, 0);
          }
        }
      }
      __builtin_amdgcn_s_setprio(0);
      // online softmax (fp32, true units: S*2^-24); p kept in S[][] registers
      #pragma unroll
      for (int mt = 0; mt < 2; mt++)
        #pragma unroll
        for (int r = 0; r < 4; r++) {
          const int q_g = qt * 128 + wid * 32 + mt * 16 + ((lane >> 4) << 2) + r;
          float sv[4];
          float tm = -1e30f;
          #pragma unroll
          for (int nt = 0; nt < 4; nt++) {
            const int kp = s0 + nt * 16 + (lane & 15);
            sv[nt] = (kp <= q_g) ? S[mt][nt][r] * S_UNSCALE : -1e30f;
            tm = fmaxf(tm, sv[nt]);
          }
          tm = fmaxf(tm, __shfl_xor(tm, 1, 64));
          tm = fmaxf(tm, __shfl_xor(tm, 2, 64));
          tm = fmaxf(tm, __shfl_xor(tm, 4, 64));
          tm = fmaxf(tm, __shfl_xor(tm, 8, 64));
          const float nm = fmaxf(mrun[mt][r], tm);
          const float rs = __expf(mrun[mt][r] - nm);
          mrun[mt][r] = nm;
          float ps = 0.0f;
          #pragma unroll
          for (int nt = 0; nt < 4; nt++) {
            const float p = (sv[nt] > -1e29f) ? __expf(sv[nt] - nm) : 0.0f;
            ps += p;
            S[mt][nt][r] = p;                    // buffer p (<=1) in registers
          }
          ps += __shfl_xor(ps, 1, 64);
          ps += __shfl_xor(ps, 2, 64);
          ps += __shfl_xor(ps, 4, 64);
          ps += __shfl_xor(ps, 8, 64);
          // T13: rs == 1.0f exactly when the running max didn't grow -> skip
          if (rs != 1.0f) {
            lsum[mt][r] = lsum[mt][r] * rs + ps;
            #pragma unroll
            for (int nt = 0; nt < 8; nt++) O[mt][nt][r] *= rs;
          } else {
            lsum[mt][r] += ps;
          }
        }
    }
    __syncthreads();   // all waves done reading K tile -> safe to overwrite with P

    if (active) {
      // P*2^14 (f16 hi/lo) -> wave-private quarter of the dead K tile
      #pragma unroll
      for (int mt = 0; mt < 2; mt++)
        #pragma unroll
        for (int r = 0; r < 4; r++) {
          const int q_l = mt * 16 + ((lane >> 4) << 2) + r;
          #pragma unroll
          for (int nt = 0; nt < 4; nt++) {
            const int kp_l = nt * 16 + (lane & 15);
            const int ch = kp_l >> 3;
            const int idx = q_l * 64 + ((ch ^ (q_l & 7)) << 3) + (kp_l & 7);
            splitf16(S[mt][nt][r] * P_SCALE, PH[idx], PL[idx]);
          }
        }
      // O += P.V (3-term hi/lo)
      #pragma unroll
      for (int kc = 0; kc < 2; kc++) {
        f16x8 pa[2], pb[2];
        #pragma unroll
        for (int mt = 0; mt < 2; mt++) {
          const int rq = mt * 16 + (lane & 15);
          const int ch = kc * 4 + (lane >> 4);
          const int idx = rq * 64 + ((ch ^ (rq & 7)) << 3);
          pa[mt] = *(const f16x8*)&PH[idx];
          pb[mt] = *(const f16x8*)&PL[idx];
        }
        __builtin_amdgcn_s_setprio(1);
        #pragma unroll
        for (int nt = 0; nt < 8; nt++) {
          const int rd = nt * 16 + (lane & 15);
          const int ch = kc * 4 + (lane >> 4);
          const int idx = rd * 64 + ((ch ^ (rd & 7)) << 3);
          const f16x8 vh = *(const f16x8*)(VH + idx);
          const f16x8 vl = *(const f16x8*)(VL + idx);
          #pragma unroll
          for (int mt = 0; mt < 2; mt++) {
            O[mt][nt] = __builtin_amdgcn_mfma_f32_16x16x32_f16(pa[mt], vh, O[mt][nt], 0, 0, 0);
            O[mt][nt] = __builtin_amdgcn_mfma_f32_16x16x32_f16(pb[mt], vh, O[mt][nt], 0, 0, 0);
            O[mt][nt] = __builtin_amdgcn_mfma_f32_16x16x32_f16(pa[mt], vl, O[mt][nt], 0, 0, 0);
          }
        }
        __builtin_amdgcn_s_setprio(0);
      }
    }
    __syncthreads();   // P / V tile consumed before next staging overwrites
  }

  // epilogue: normalize (incl. 2^-20 unscale), store attn [s][h*128+d], absmax
  float am = 0.0f;
  #pragma unroll
  for (int mt = 0; mt < 2; mt++)
    #pragma unroll
    for (int r = 0; r < 4; r++) {
      const int q_g = qt * 128 + wid * 32 + mt * 16 + ((lane >> 4) << 2) + r;
      const float inv = O_UNSCALE / lsum[mt][r];
      #pragma unroll
      for (int nt = 0; nt < 8; nt++) {
        const float val = O[mt][nt][r] * inv;
        attn[(long long)q_g * HID + h * HD + nt * 16 + (lane & 15)] = val;
        am = fmaxf(am, fabsf(val));
      }
    }
  am = fmaxf(am, __shfl_xor(am, 1, 64));
  am = fmaxf(am, __shfl_xor(am, 2, 64));
  am = fmaxf(am, __shfl_xor(am, 4, 64));
  am = fmaxf(am, __shfl_xor(am, 8, 64));
  am = fmaxf(am, __shfl_xor(am, 16, 64));
  am = fmaxf(am, __shfl_xor(am, 32, 64));
  if (lane == 0) atomicMax(amax, __float_as_uint(am));
}

// ---------------------------------------------------------------------------
extern "C" void kernel_launch(void* const* d_in, const int* in_sizes, int n_in,
                              void* d_out, int out_size, void* d_ws, size_t ws_size,
                              hipStream_t stream) {
  const float* hidden = (const float*)d_in[0];
  const float* cosb   = (const float*)d_in[1];
  const float* sinb   = (const float*)d_in[2];
  const float* wq     = (const float*)d_in[3];
  const float* bq     = (const float*)d_in[4];
  const float* wk     = (const float*)d_in[5];
  const float* bk     = (const float*)d_in[6];
  const float* wv     = (const float*)d_in[7];
  const float* bv     = (const float*)d_in[8];
  const float* wo     = (const float*)d_in[9];
  float* out = (float*)d_out;

  char* w = (char*)d_ws;
  size_t off = 0;
  auto alloc = [&](size_t bytes) -> void* {
    void* p = w + off;
    off += (bytes + 255) & ~(size_t)255;
    return p;
  };
  unsigned* scal = (unsigned*)alloc(256);                        // [0]=amax_x [1]=amax_attn
  i8* xq8   = (i8*)alloc((size_t)S_LEN * KD);                    // also reused for attn int8
  i8* wq8   = (i8*)alloc((size_t)HID * KD);
  i8* wk8   = (i8*)alloc((size_t)NKV * HD * KD);
  i8* wv8   = (i8*)alloc((size_t)NKV * HD * KD);
  i8* wo8   = (i8*)alloc((size_t)HID * KD);
  float* swq = (float*)alloc(HID * 4);
  float* swk = (float*)alloc(NKV * HD * 4);
  float* swv = (float*)alloc(NKV * HD * 4);
  float* swo = (float*)alloc(HID * 4);
  u16* qhi_  = (u16*)alloc((size_t)NH * S_LEN * HD * 2);
  u16* qlo_  = (u16*)alloc((size_t)NH * S_LEN * HD * 2);
  u16* khi_  = (u16*)alloc((size_t)NKV * S_LEN * HD * 2);
  u16* klo_  = (u16*)alloc((size_t)NKV * S_LEN * HD * 2);
  u16* vthi_ = (u16*)alloc((size_t)NKV * S_LEN * HD * 2);
  u16* vtlo_ = (u16*)alloc((size_t)NKV * S_LEN * HD * 2);
  float* attnb = (float*)alloc((size_t)S_LEN * HID * 4);

  const long long nact = (long long)S_LEN * KD;  // 7,340,032

  k_zero<<<1, 64, 0, stream>>>((float*)scal);
  k_absmax<<<1024, 256, 0, stream>>>(hidden, nact, scal + 0);
  k_quant_w<<<HID, 256, 0, stream>>>(wq, wq8, swq);
  k_quant_w<<<NKV * HD, 256, 0, stream>>>(wk, wk8, swk);
  k_quant_w<<<NKV * HD, 256, 0, stream>>>(wv, wv8, swv);
  k_quant_w<<<HID, 256, 0, stream>>>(wo, wo8, swo);
  k_quant_act<<<(int)(nact / 4 / 256), 256, 0, stream>>>(hidden, xq8, scal + 0, nact);

  // fused QKV projection + rope + f16 split (36 ct x 16 mb = 576 blocks)
  k_gemm<<<dim3(36 * 16), 256, 0, stream>>>(
      xq8, wq8, wk8, wv8, swq, swk, swv, bq, bk, bv, cosb, sinb, scal + 0,
      qhi_, qlo_, khi_, klo_, vthi_, vtlo_, nullptr, 0);

  k_attn<<<dim3(NH, 16), 256, 0, stream>>>(qhi_, qlo_, khi_, klo_, vthi_, vtlo_,
                                           attnb, scal + 1);

  k_quant_act<<<(int)(nact / 4 / 256), 256, 0, stream>>>(attnb, xq8, scal + 1, nact);

  // O projection -> d_out (fp32)  (28 ct x 16 mb = 448 blocks)
  k_gemm<<<dim3(28 * 16), 256, 0, stream>>>(
      xq8, wo8, nullptr, nullptr, swo, nullptr, nullptr, nullptr, nullptr, nullptr,
      nullptr, nullptr, scal + 1,
      nullptr, nullptr, nullptr, nullptr, nullptr, nullptr, out, 1);
}

// Round 5
// 558.107 us; speedup vs baseline: 1.1455x; 1.1455x over previous
//
#include <hip/hip_runtime.h>
#include <stdint.h>

// ---------------------------------------------------------------------------
// QuantQwenAttentionV2 fused pipeline, MI355X (gfx950)
//
//  k_zero       : zero amax scalars in ws
//  k_absmax     : per-tensor absmax of hidden (atomicMax on float bits)
//  k_quant_w    : per-row 4-bit weight fake-quant -> int8 [-8,7] + scale
//  k_quant_act  : per-tensor 8-bit activation fake-quant -> int8 [-128,127]
//  k_gemm       : int8 MFMA GEMM (exact integer path), fused epilogues:
//                   epi0: Q  = rope(y)*2^12/sqrt(d) -> f16 hi/lo [h][s][d]
//                   epi1: K  = rope(y)*2^12         -> f16 hi/lo [g][s][d]
//                   epi2: V  = y*2^6                -> f16 hi/lo transposed [g][d][s]
//                   epi3: O-proj -> fp32 d_out
//                 1-D grid, XCD-chunked bijective swizzle (T1/m204).
//  k_attn       : flash attention v2. Pair-balanced causal schedule: block
//                 (h, p) processes q-tiles qt=15-p then qt=p sequentially
//                 (34 uniform k-steps per block). K/V double-buffered in LDS
//                 (128KB) with prefetch-at-top-of-step so staging hides under
//                 QK^T MFMA. 3-term hi/lo f16 MFMA (~fp32 accurate), fp32
//                 online softmax (T13), P aliases dead cur-K buffer.
// ---------------------------------------------------------------------------

#define S_LEN 2048
#define HID   3584
#define NH    28
#define NKV   4
#define HD    128
#define GQA   7      // NH / NKV
#define KD    3584   // inner dim of projections

typedef signed char i8;
typedef unsigned short u16;
typedef __attribute__((ext_vector_type(4))) int      v4i;
typedef __attribute__((ext_vector_type(4))) float    v4f;
typedef __attribute__((ext_vector_type(8))) _Float16 f16x8;  // 8 f16 (4 VGPRs)
typedef __attribute__((ext_vector_type(4))) float    f32x4;

// scales (powers of 2, folded into existing multiplies; keep f16 residuals normal)
#define QK_SCALE   4096.0f                    // 2^12 on Q and on K
#define S_UNSCALE  5.9604644775390625e-8f     // 2^-24
#define V_SCALE    64.0f                      // 2^6
#define P_SCALE    16384.0f                   // 2^14
#define O_UNSCALE  9.5367431640625e-7f        // 2^-20

#define GLOAD_LDS(g, l) __builtin_amdgcn_global_load_lds( \
    (__attribute__((address_space(1))) void*)(g),          \
    (__attribute__((address_space(3))) void*)(l), 16, 0, 0)

static __device__ __forceinline__ u16 f16bits(_Float16 h) {
  u16 u; __builtin_memcpy(&u, &h, 2); return u;
}
// split x into f16 hi + f16 lo (hi = RNE(x), lo = RNE(x - hi)); ~22-bit total
static __device__ __forceinline__ void splitf16(float x, u16& hb, u16& lb) {
  _Float16 h = (_Float16)x;
  float r = x - (float)h;          // exact (Sterbenz)
  _Float16 l = (_Float16)r;
  hb = f16bits(h); lb = f16bits(l);
}

// ---------------------------------------------------------------------------
__global__ void k_zero(float* p) {
  if (threadIdx.x < 8) p[threadIdx.x] = 0.0f;
}

// grid-stride absmax over n floats (n % 4 == 0), atomicMax on positive float bits
__global__ void k_absmax(const float* __restrict__ x, long long n, unsigned* __restrict__ out) {
  long long i0 = ((long long)blockIdx.x * blockDim.x + threadIdx.x) * 4;
  long long stride = (long long)gridDim.x * blockDim.x * 4;
  float m = 0.0f;
  for (long long i = i0; i < n; i += stride) {
    f32x4 v = *(const f32x4*)(x + i);
    m = fmaxf(m, fmaxf(fmaxf(fabsf(v.x), fabsf(v.y)), fmaxf(fabsf(v.z), fabsf(v.w))));
  }
  #pragma unroll
  for (int o = 32; o > 0; o >>= 1) m = fmaxf(m, __shfl_xor(m, o, 64));
  __shared__ float sm[4];
  if ((threadIdx.x & 63) == 0) sm[threadIdx.x >> 6] = m;
  __syncthreads();
  if (threadIdx.x == 0) {
    m = fmaxf(fmaxf(sm[0], sm[1]), fmaxf(sm[2], sm[3]));
    atomicMax(out, __float_as_uint(m));
  }
}

// per-tensor 8-bit symmetric fake-quant -> int8
__global__ void k_quant_act(const float* __restrict__ x, i8* __restrict__ q,
                            const unsigned* __restrict__ amax, long long n) {
  float s = fmaxf(__uint_as_float(*amax) / 127.0f, 1e-8f);
  long long i = ((long long)blockIdx.x * blockDim.x + threadIdx.x) * 4;
  if (i >= n) return;
  f32x4 v = *(const f32x4*)(x + i);
  char4 c;
  c.x = (char)fminf(fmaxf(rintf(v.x / s), -128.0f), 127.0f);
  c.y = (char)fminf(fmaxf(rintf(v.y / s), -128.0f), 127.0f);
  c.z = (char)fminf(fmaxf(rintf(v.z / s), -128.0f), 127.0f);
  c.w = (char)fminf(fmaxf(rintf(v.w / s), -128.0f), 127.0f);
  *(char4*)(q + i) = c;
}

// per-row 4-bit symmetric weight fake-quant -> int8 in [-8,7]; one block per row
__global__ void k_quant_w(const float* __restrict__ w, i8* __restrict__ wq,
                          float* __restrict__ sw) {
  const int row = blockIdx.x;
  const float2* wr = (const float2*)(w + (long long)row * KD);
  float2 v[7];
  float m = 0.0f;
  #pragma unroll
  for (int j = 0; j < 7; j++) {            // 1792 float2 = 3584 floats
    v[j] = wr[threadIdx.x + 256 * j];
    m = fmaxf(m, fmaxf(fabsf(v[j].x), fabsf(v[j].y)));
  }
  #pragma unroll
  for (int o = 32; o > 0; o >>= 1) m = fmaxf(m, __shfl_xor(m, o, 64));
  __shared__ float sm[4];
  if ((threadIdx.x & 63) == 0) sm[threadIdx.x >> 6] = m;
  __syncthreads();
  const float mm = fmaxf(fmaxf(sm[0], sm[1]), fmaxf(sm[2], sm[3]));
  const float s = fmaxf(mm / 7.0f, 1e-8f);
  if (threadIdx.x == 0) sw[row] = s;
  u16* o = (u16*)(wq + (long long)row * KD);
  #pragma unroll
  for (int j = 0; j < 7; j++) {
    const int c0 = (int)fminf(fmaxf(rintf(v[j].x / s), -8.0f), 7.0f);
    const int c1 = (int)fminf(fmaxf(rintf(v[j].y / s), -8.0f), 7.0f);
    o[threadIdx.x + 256 * j] = (u16)((c0 & 0xff) | ((c1 & 0xff) << 8));
  }
}

// ---------------------------------------------------------------------------
// int8 GEMM: C[m][n] = s_a*sw[n]*sum_k A[m,k]*W[n,k] (+bias), fused epilogues.
// Block: 256 thr (4 waves, wave tile 32x128). BM=BN=128, BK=64.
// LDS tiles [128][64] i8; 16B chunks XOR-swizzled with ((row>>1)&3).
// kind==0: QKV fused over 36 col-tiles; kind==1: O-projection.
__global__ __launch_bounds__(256, 3) void k_gemm(
    const i8* __restrict__ Aq,
    const i8* __restrict__ W0, const i8* __restrict__ W1, const i8* __restrict__ W2,
    const float* __restrict__ sw0, const float* __restrict__ sw1, const float* __restrict__ sw2,
    const float* __restrict__ b0, const float* __restrict__ b1, const float* __restrict__ b2,
    const float* __restrict__ cosb, const float* __restrict__ sinb,
    const unsigned* __restrict__ amax_slot,
    u16* __restrict__ qhi, u16* __restrict__ qlo,
    u16* __restrict__ khi, u16* __restrict__ klo,
    u16* __restrict__ vthi, u16* __restrict__ vtlo,
    float* __restrict__ outO, int kind) {
  __shared__ i8 As[128 * 64];
  __shared__ i8 Bs[128 * 64];
  const int tid = threadIdx.x, wid = tid >> 6, lane = tid & 63;

  // bijective XCD chunking (m204): orig%8 = XCD, chunk of nwg/8 work items
  const int q8 = (int)gridDim.x >> 3;
  const int orig = blockIdx.x;
  const int wgid = (orig & 7) * q8 + (orig >> 3);
  const int ct = wgid >> 4;     // 16 mb-tiles per ct
  const int mb = wgid & 15;

  const i8* Bw; const float* sw; const float* bias; int epi; int nbase;
  if (kind == 1)      { Bw = W0; sw = sw0; bias = nullptr; epi = 3; nbase = ct * 128; }
  else if (ct < 28)   { Bw = W0; sw = sw0; bias = b0;      epi = 0; nbase = ct * 128; }
  else if (ct < 32)   { Bw = W1; sw = sw1; bias = b1;      epi = 1; nbase = (ct - 28) * 128; }
  else                { Bw = W2; sw = sw2; bias = b2;      epi = 2; nbase = (ct - 32) * 128; }

  const float s_a = fmaxf(__uint_as_float(*amax_slot) / 127.0f, 1e-8f);

  v4i acc[2][8];
  #pragma unroll
  for (int a = 0; a < 2; a++)
    #pragma unroll
    for (int b = 0; b < 8; b++) acc[a][b] = (v4i)(0);

  const long long arow0 = (long long)mb * 128 * KD;
  const long long brow0 = (long long)nbase * KD;

  for (int kt = 0; kt < KD / 64; ++kt) {
    const int k0 = kt * 64;
    #pragma unroll
    for (int j = 0; j < 2; j++) {
      const int c = tid + 256 * j;
      const int r = c >> 2, seg = c & 3;
      const int so = (seg ^ ((r >> 1) & 3)) << 4;  // pre-swizzled global source
      GLOAD_LDS(Aq + arow0 + (long long)r * KD + k0 + so, As + c * 16);
      GLOAD_LDS(Bw + brow0 + (long long)r * KD + k0 + so, Bs + c * 16);
    }
    __syncthreads();
    v4i af[2];
    #pragma unroll
    for (int mt = 0; mt < 2; mt++) {
      const int rl = wid * 32 + mt * 16 + (lane & 15);
      af[mt] = *(const v4i*)(As + rl * 64 + ((((lane >> 4)) ^ ((rl >> 1) & 3)) << 4));
    }
    #pragma unroll
    for (int nt = 0; nt < 8; nt++) {
      const int rb = nt * 16 + (lane & 15);
      const v4i bfr = *(const v4i*)(Bs + rb * 64 + ((((lane >> 4)) ^ ((rb >> 1) & 3)) << 4));
      acc[0][nt] = __builtin_amdgcn_mfma_i32_16x16x64_i8(af[0], bfr, acc[0][nt], 0, 0, 0);
      acc[1][nt] = __builtin_amdgcn_mfma_i32_16x16x64_i8(af[1], bfr, acc[1][nt], 0, 0, 0);
    }
    __syncthreads();
  }

  // ---- epilogue (C layout: col n = lane&15 + 16*nt, row m = (lane>>4)*4 + r) --
  float y[2][8][4];
  #pragma unroll
  for (int mt = 0; mt < 2; mt++)
    #pragma unroll
    for (int nt = 0; nt < 8; nt++) {
      const int n = nbase + nt * 16 + (lane & 15);
      const float sc = s_a * sw[n];
      const float bb = bias ? bias[n] : 0.0f;
      #pragma unroll
      for (int r = 0; r < 4; r++) y[mt][nt][r] = sc * (float)acc[mt][nt][r] + bb;
    }

  if (epi == 3) {  // O-projection: plain fp32 store
    #pragma unroll
    for (int mt = 0; mt < 2; mt++)
      #pragma unroll
      for (int r = 0; r < 4; r++) {
        const int m_ = mb * 128 + wid * 32 + mt * 16 + ((lane >> 4) << 2) + r;
        #pragma unroll
        for (int nt = 0; nt < 8; nt++)
          outO[(long long)m_ * HID + ct * 128 + nt * 16 + (lane & 15)] = y[mt][nt][r];
      }
  } else if (epi == 2) {  // V: f16 hi/lo split of V*2^6, stored transposed [g][d][s]
    const int gkv = ct - 32;
    #pragma unroll
    for (int mt = 0; mt < 2; mt++)
      #pragma unroll
      for (int nt = 0; nt < 8; nt++) {
        const int d = nt * 16 + (lane & 15);
        const int mbase = mb * 128 + wid * 32 + mt * 16 + ((lane >> 4) << 2);
        ushort4 hv, lv;
        #pragma unroll
        for (int r = 0; r < 4; r++)
          splitf16(y[mt][nt][r] * V_SCALE, ((u16*)&hv)[r], ((u16*)&lv)[r]);
        const long long o = ((long long)(gkv * HD + d)) * S_LEN + mbase;
        *(ushort4*)(vthi + o) = hv;
        *(ushort4*)(vtlo + o) = lv;
      }
  } else {  // Q (epi 0) / K (epi 1): multimodal RoPE, f16 hi/lo of (rope)*scale
    const int head = (epi == 0) ? ct : (ct - 28);
    u16* oh = (epi == 0) ? qhi : khi;
    u16* ol = (epi == 0) ? qlo : klo;
    // Q: 1/sqrt(128) * 2^12 ; K: 2^12
    const float qs = (epi == 0) ? 0.08838834764831845f * QK_SCALE : QK_SCALE;
    #pragma unroll
    for (int mt = 0; mt < 2; mt++)
      #pragma unroll
      for (int r = 0; r < 4; r++) {
        const int m_ = mb * 128 + wid * 32 + mt * 16 + ((lane >> 4) << 2) + r;
        #pragma unroll
        for (int nt = 0; nt < 8; nt++) {
          const int d = nt * 16 + (lane & 15);
          const int sec = (d < 32) ? 0 : ((d < 80) ? 1 : 2);  // mrope [16,24,24]*2
          const long long ci = ((long long)sec * S_LEN + m_) * HD + d;
          const float c = cosb[ci], s = sinb[ci];
          const float part = (nt < 4) ? -y[mt][nt + 4][r] : y[mt][nt - 4][r];
          const float e = (y[mt][nt][r] * c + part * s) * qs;
          const long long o = ((long long)head * S_LEN + m_) * HD + d;
          splitf16(e, oh[o], ol[o]);
        }
      }
  }
}

// ---------------------------------------------------------------------------
// Flash attention v2: pair-balanced + double-buffered staging.
// Grid: 224 blocks (28 heads x 8 pairs), XCD-chunked swizzle. Block processes
// q-tile qt=15-p then qt=p (ktB+ktA = 34 k-steps, uniform across blocks).
// Per k-step: issue prefetch of tile s+1 into buf^1, QK^T from buf (3-term
// f16 MFMA), softmax (T13), barrier, P->dead cur-K quarter, PV, barrier.
// LDS 128KB (1 block/CU); staging latency hides under ~1900cy QK^T MFMA.
__global__ __launch_bounds__(256, 1) void k_attn(
    const u16* __restrict__ qhi, const u16* __restrict__ qlo,
    const u16* __restrict__ khi, const u16* __restrict__ klo,
    const u16* __restrict__ vthi, const u16* __restrict__ vtlo,
    float* __restrict__ attn, unsigned* __restrict__ amax) {
  // XCD-chunked bijective swizzle over 1-D grid (id = h*8 + p, h-major)
  const int orig = blockIdx.x;
  const int nchunk = (int)gridDim.x >> 3;               // 28
  const int swz = (orig & 7) * nchunk + (orig >> 3);
  const int h = swz >> 3;
  const int p = swz & 7;
  const int g = h / GQA;
  const int tid = threadIdx.x, wid = tid >> 6, lane = tid & 63;

  __shared__ u16 KH[2][64 * 128], KL[2][64 * 128];   // [buf][kpos][d], swizzled
  __shared__ u16 VH[2][128 * 64], VL[2][128 * 64];   // [buf][d][kpos], swizzled

#define STAGE(b, t) do {                                                        \
    const int s0_ = (t) * 64;                                                   \
    _Pragma("unroll")                                                           \
    for (int j_ = 0; j_ < 4; j_++) {                                            \
      const int c_ = tid + 256 * j_;                                            \
      const int r_ = c_ >> 4, sg_ = c_ & 15;                                    \
      const long long gb_ = ((long long)g * S_LEN + s0_ + r_) * HD +            \
                            ((sg_ ^ (r_ & 7)) << 3);                            \
      GLOAD_LDS(khi + gb_, (i8*)KH[(b)] + c_ * 16);                             \
      GLOAD_LDS(klo + gb_, (i8*)KL[(b)] + c_ * 16);                             \
    }                                                                           \
    _Pragma("unroll")                                                           \
    for (int j_ = 0; j_ < 4; j_++) {                                            \
      const int c_ = tid + 256 * j_;                                            \
      const int d_ = c_ >> 3, sg_ = c_ & 7;                                     \
      const long long gb_ = ((long long)(g * HD + d_)) * S_LEN + s0_ +          \
                            ((sg_ ^ (d_ & 7)) << 3);                            \
      GLOAD_LDS(vthi + gb_, (i8*)VH[(b)] + c_ * 16);                            \
      GLOAD_LDS(vtlo + gb_, (i8*)VL[(b)] + c_ * 16);                            \
    }                                                                           \
  } while (0)

  float am = 0.0f;

  for (int pass = 0; pass < 2; ++pass) {
    const int qt = pass ? p : 15 - p;
    const int ktn = 2 * qt + 2;

    STAGE(0, 0);   // prologue stage of tile 0 (overlaps Q loads below)

    // Q fragments (A-operand: row = lane&15, k chunk = lane>>4)
    f16x8 qh[2][4], ql[2][4];
    #pragma unroll
    for (int mt = 0; mt < 2; mt++) {
      const int row = qt * 128 + wid * 32 + mt * 16 + (lane & 15);
      const long long base = ((long long)h * S_LEN + row) * HD + ((lane >> 4) << 3);
      #pragma unroll
      for (int kc = 0; kc < 4; kc++) {
        qh[mt][kc] = *(const f16x8*)(qhi + base + kc * 32);
        ql[mt][kc] = *(const f16x8*)(qlo + base + kc * 32);
      }
    }

    v4f O[2][8];
    #pragma unroll
    for (int a = 0; a < 2; a++)
      #pragma unroll
      for (int b = 0; b < 8; b++) O[a][b] = (v4f)(0.0f);
    float mrun[2][4], lsum[2][4];
    #pragma unroll
    for (int a = 0; a < 2; a++)
      #pragma unroll
      for (int r = 0; r < 4; r++) { mrun[a][r] = -1e30f; lsum[a][r] = 0.0f; }

    const int qmaxw = qt * 128 + wid * 32 + 31;
    __syncthreads();   // tile 0 staged (implicit vmcnt(0) drain)

    for (int s = 0; s < ktn; ++s) {
      const int cur = s & 1;
      const int s0 = s * 64;
      u16* PH = KH[cur] + wid * 2048;     // per-wave P quarter of dead K tile
      u16* PL = KL[cur] + wid * 2048;

      if (s + 1 < ktn) STAGE(cur ^ 1, s + 1);   // prefetch; hides under QK^T

      const bool active = (s0 <= qmaxw);  // wave-uniform causal skip
      v4f S[2][4];
      if (active) {
        #pragma unroll
        for (int a = 0; a < 2; a++)
          #pragma unroll
          for (int b = 0; b < 4; b++) S[a][b] = (v4f)(0.0f);
        __builtin_amdgcn_s_setprio(1);
        #pragma unroll
        for (int kc = 0; kc < 4; kc++) {
          #pragma unroll
          for (int nt = 0; nt < 4; nt++) {
            const int rk = nt * 16 + (lane & 15);
            const int ch = kc * 4 + (lane >> 4);
            const int idx = rk * 128 + ((ch ^ (rk & 7)) << 3);
            const f16x8 kh = *(const f16x8*)(KH[cur] + idx);
            const f16x8 kl = *(const f16x8*)(KL[cur] + idx);
            #pragma unroll
            for (int mt = 0; mt < 2; mt++) {
              S[mt][nt] = __builtin_amdgcn_mfma_f32_16x16x32_f16(qh[mt][kc], kh, S[mt][nt], 0, 0, 0);
              S[mt][nt] = __builtin_amdgcn_mfma_f32_16x16x32_f16(qh[mt][kc], kl, S[mt][nt], 0, 0, 0);
              S[mt][nt] = __builtin_amdgcn_mfma_f32_16x16x32_f16(ql[mt][kc], kh, S[mt][nt], 0, 0, 0);
            }
          }
        }
        __builtin_amdgcn_s_setprio(0);
        // online softmax (fp32, true units: S*2^-24); p kept in S[][] registers
        #pragma unroll
        for (int mt = 0; mt < 2; mt++)
          #pragma unroll
          for (int r = 0; r < 4; r++) {
            const int q_g = qt * 128 + wid * 32 + mt * 16 + ((lane >> 4) << 2) + r;
            float sv[4];
            float tm = -1e30f;
            #pragma unroll
            for (int nt = 0; nt < 4; nt++) {
              const int kp = s0 + nt * 16 + (lane & 15);
              sv[nt] = (kp <= q_g) ? S[mt][nt][r] * S_UNSCALE : -1e30f;
              tm = fmaxf(tm, sv[nt]);
            }
            tm = fmaxf(tm, __shfl_xor(tm, 1, 64));
            tm = fmaxf(tm, __shfl_xor(tm, 2, 64));
            tm = fmaxf(tm, __shfl_xor(tm, 4, 64));
            tm = fmaxf(tm, __shfl_xor(tm, 8, 64));
            const float nm = fmaxf(mrun[mt][r], tm);
            const float rs = __expf(mrun[mt][r] - nm);
            mrun[mt][r] = nm;
            float ps = 0.0f;
            #pragma unroll
            for (int nt = 0; nt < 4; nt++) {
              const float pv = (sv[nt] > -1e29f) ? __expf(sv[nt] - nm) : 0.0f;
              ps += pv;
              S[mt][nt][r] = pv;                 // buffer p (<=1) in registers
            }
            ps += __shfl_xor(ps, 1, 64);
            ps += __shfl_xor(ps, 2, 64);
            ps += __shfl_xor(ps, 4, 64);
            ps += __shfl_xor(ps, 8, 64);
            // T13: rs == 1.0f exactly when the running max didn't grow -> skip
            if (rs != 1.0f) {
              lsum[mt][r] = lsum[mt][r] * rs + ps;
              #pragma unroll
              for (int nt = 0; nt < 8; nt++) O[mt][nt][r] *= rs;
            } else {
              lsum[mt][r] += ps;
            }
          }
      }
      __syncthreads();   // all waves done reading K[cur]; prefetch drained

      if (active) {
        // P*2^14 (f16 hi/lo) -> wave-private quarter of the dead K tile
        #pragma unroll
        for (int mt = 0; mt < 2; mt++)
          #pragma unroll
          for (int r = 0; r < 4; r++) {
            const int q_l = mt * 16 + ((lane >> 4) << 2) + r;
            #pragma unroll
            for (int nt = 0; nt < 4; nt++) {
              const int kp_l = nt * 16 + (lane & 15);
              const int ch = kp_l >> 3;
              const int idx = q_l * 64 + ((ch ^ (q_l & 7)) << 3) + (kp_l & 7);
              splitf16(S[mt][nt][r] * P_SCALE, PH[idx], PL[idx]);
            }
          }
        // O += P.V (3-term hi/lo)
        #pragma unroll
        for (int kc = 0; kc < 2; kc++) {
          f16x8 pa[2], pb[2];
          #pragma unroll
          for (int mt = 0; mt < 2; mt++) {
            const int rq = mt * 16 + (lane & 15);
            const int ch = kc * 4 + (lane >> 4);
            const int idx = rq * 64 + ((ch ^ (rq & 7)) << 3);
            pa[mt] = *(const f16x8*)&PH[idx];
            pb[mt] = *(const f16x8*)&PL[idx];
          }
          __builtin_amdgcn_s_setprio(1);
          #pragma unroll
          for (int nt = 0; nt < 8; nt++) {
            const int rd = nt * 16 + (lane & 15);
            const int ch = kc * 4 + (lane >> 4);
            const int idx = rd * 64 + ((ch ^ (rd & 7)) << 3);
            const f16x8 vh = *(const f16x8*)(VH[cur] + idx);
            const f16x8 vl = *(const f16x8*)(VL[cur] + idx);
            #pragma unroll
            for (int mt = 0; mt < 2; mt++) {
              O[mt][nt] = __builtin_amdgcn_mfma_f32_16x16x32_f16(pa[mt], vh, O[mt][nt], 0, 0, 0);
              O[mt][nt] = __builtin_amdgcn_mfma_f32_16x16x32_f16(pb[mt], vh, O[mt][nt], 0, 0, 0);
              O[mt][nt] = __builtin_amdgcn_mfma_f32_16x16x32_f16(pa[mt], vl, O[mt][nt], 0, 0, 0);
            }
          }
          __builtin_amdgcn_s_setprio(0);
        }
      }
      __syncthreads();   // P / V[cur] consumed; next step may overwrite
    }

    // epilogue: normalize (incl. 2^-20 unscale), store attn [s][h*128+d]
    #pragma unroll
    for (int mt = 0; mt < 2; mt++)
      #pragma unroll
      for (int r = 0; r < 4; r++) {
        const int q_g = qt * 128 + wid * 32 + mt * 16 + ((lane >> 4) << 2) + r;
        const float inv = O_UNSCALE / lsum[mt][r];
        #pragma unroll
        for (int nt = 0; nt < 8; nt++) {
          const float val = O[mt][nt][r] * inv;
          attn[(long long)q_g * HID + h * HD + nt * 16 + (lane & 15)] = val;
          am = fmaxf(am, fabsf(val));
        }
      }
  }
#undef STAGE

  am = fmaxf(am, __shfl_xor(am, 1, 64));
  am = fmaxf(am, __shfl_xor(am, 2, 64));
  am = fmaxf(am, __shfl_xor(am, 4, 64));
  am = fmaxf(am, __shfl_xor(am, 8, 64));
  am = fmaxf(am, __shfl_xor(am, 16, 64));
  am = fmaxf(am, __shfl_xor(am, 32, 64));
  if (lane == 0) atomicMax(amax, __float_as_uint(am));
}

// ---------------------------------------------------------------------------
extern "C" void kernel_launch(void* const* d_in, const int* in_sizes, int n_in,
                              void* d_out, int out_size, void* d_ws, size_t ws_size,
                              hipStream_t stream) {
  const float* hidden = (const float*)d_in[0];
  const float* cosb   = (const float*)d_in[1];
  const float* sinb   = (const float*)d_in[2];
  const float* wq     = (const float*)d_in[3];
  const float* bq     = (const float*)d_in[4];
  const float* wk     = (const float*)d_in[5];
  const float* bk     = (const float*)d_in[6];
  const float* wv     = (const float*)d_in[7];
  const float* bv     = (const float*)d_in[8];
  const float* wo     = (const float*)d_in[9];
  float* out = (float*)d_out;

  char* w = (char*)d_ws;
  size_t off = 0;
  auto alloc = [&](size_t bytes) -> void* {
    void* p = w + off;
    off += (bytes + 255) & ~(size_t)255;
    return p;
  };
  unsigned* scal = (unsigned*)alloc(256);                        // [0]=amax_x [1]=amax_attn
  i8* xq8   = (i8*)alloc((size_t)S_LEN * KD);                    // also reused for attn int8
  i8* wq8   = (i8*)alloc((size_t)HID * KD);
  i8* wk8   = (i8*)alloc((size_t)NKV * HD * KD);
  i8* wv8   = (i8*)alloc((size_t)NKV * HD * KD);
  i8* wo8   = (i8*)alloc((size_t)HID * KD);
  float* swq = (float*)alloc(HID * 4);
  float* swk = (float*)alloc(NKV * HD * 4);
  float* swv = (float*)alloc(NKV * HD * 4);
  float* swo = (float*)alloc(HID * 4);
  u16* qhi_  = (u16*)alloc((size_t)NH * S_LEN * HD * 2);
  u16* qlo_  = (u16*)alloc((size_t)NH * S_LEN * HD * 2);
  u16* khi_  = (u16*)alloc((size_t)NKV * S_LEN * HD * 2);
  u16* klo_  = (u16*)alloc((size_t)NKV * S_LEN * HD * 2);
  u16* vthi_ = (u16*)alloc((size_t)NKV * S_LEN * HD * 2);
  u16* vtlo_ = (u16*)alloc((size_t)NKV * S_LEN * HD * 2);
  float* attnb = (float*)alloc((size_t)S_LEN * HID * 4);

  const long long nact = (long long)S_LEN * KD;  // 7,340,032

  k_zero<<<1, 64, 0, stream>>>((float*)scal);
  k_absmax<<<1024, 256, 0, stream>>>(hidden, nact, scal + 0);
  k_quant_w<<<HID, 256, 0, stream>>>(wq, wq8, swq);
  k_quant_w<<<NKV * HD, 256, 0, stream>>>(wk, wk8, swk);
  k_quant_w<<<NKV * HD, 256, 0, stream>>>(wv, wv8, swv);
  k_quant_w<<<HID, 256, 0, stream>>>(wo, wo8, swo);
  k_quant_act<<<(int)(nact / 4 / 256), 256, 0, stream>>>(hidden, xq8, scal + 0, nact);

  // fused QKV projection + rope + f16 split (36 ct x 16 mb = 576 blocks)
  k_gemm<<<dim3(36 * 16), 256, 0, stream>>>(
      xq8, wq8, wk8, wv8, swq, swk, swv, bq, bk, bv, cosb, sinb, scal + 0,
      qhi_, qlo_, khi_, klo_, vthi_, vtlo_, nullptr, 0);

  // pair-balanced flash attention (28 heads x 8 pairs = 224 blocks)
  k_attn<<<dim3(NH * 8), 256, 0, stream>>>(qhi_, qlo_, khi_, klo_, vthi_, vtlo_,
                                           attnb, scal + 1);

  k_quant_act<<<(int)(nact / 4 / 256), 256, 0, stream>>>(attnb, xq8, scal + 1, nact);

  // O projection -> d_out (fp32)  (28 ct x 16 mb = 448 blocks)
  k_gemm<<<dim3(28 * 16), 256, 0, stream>>>(
      xq8, wo8, nullptr, nullptr, swo, nullptr, nullptr, nullptr, nullptr, nullptr,
      nullptr, nullptr, scal + 1,
      nullptr, nullptr, nullptr, nullptr, nullptr, nullptr, out, 1);
}